// Round 10
// baseline (171.670 us; speedup 1.0000x reference)
//
#include <hip/hip_runtime.h>

#define C 128        // IN_CH == OUT_CH
#define NPB 16       // nodes per node-pre block
#define NSLAB 8      // bucket slabs (slab id = XCC_ID; keeps writers XCD-local)
#define CAP8 24      // per-slab bucket capacity (Poisson(8): P(>24) ~ 1e-6 -> ovf empty)
#define OVF_MAX 65536
#define EPT 2        // edges per thread in scatter (more blocks = more latency hiding)

typedef int   vi2 __attribute__((ext_vector_type(2)));
typedef float vf2 __attribute__((ext_vector_type(2)));

__device__ __forceinline__ unsigned bf16_bits(float x) {   // round-to-nearest-even
    unsigned u = __float_as_uint(x);
    u += 0x7FFFu + ((u >> 16) & 1u);
    return u >> 16;
}
// HW_REG_XCC_ID = hwreg 20; simm16 = 20 | (0<<6) | ((32-1)<<11) = 63508
__device__ __forceinline__ int xcd_id() {
    return (int)(__builtin_amdgcn_s_getreg(63508) & 7u);
}

// blocks [0, SB): edge scatter into XCD-private padded-CSR slabs.
// blocks [SB, SB+PB): P = x@W1[:C] (bf16), Q = x@W1[C:] (fp32).
__global__ void fused_pre_kernel(const float* __restrict__ x, const float* __restrict__ W1,
                                 unsigned short* __restrict__ P16, float* __restrict__ Q,
                                 const int* __restrict__ ei, const float* __restrict__ attr,
                                 int* __restrict__ cursor, int* __restrict__ ovf_cnt,
                                 int2* __restrict__ ovf, unsigned* __restrict__ sorted,
                                 int N, int E, int SB) {
    if ((int)blockIdx.x < SB) {
        const int slab = xcd_id();
        int* __restrict__ cur = cursor + (size_t)slab * N;
        unsigned* __restrict__ sl = sorted + ((size_t)slab * N) * CAP8;
        const int base = (blockIdx.x * 256 + threadIdx.x) * EPT;
        if (base >= E) return;
        if (base + EPT <= E) {
            const vi2 r = __builtin_nontemporal_load((const vi2*)(ei + base));
            const vi2 c = __builtin_nontemporal_load((const vi2*)(ei + (size_t)E + base));
            const vf2 a = __builtin_nontemporal_load((const vf2*)(attr + base));
            const int pos0 = atomicAdd(&cur[c.x], 1);
            const int pos1 = atomicAdd(&cur[c.y], 1);
            const unsigned v0 = (bf16_bits(a.x) << 16) | (unsigned)r.x;
            const unsigned v1 = (bf16_bits(a.y) << 16) | (unsigned)r.y;
            if (pos0 < CAP8) sl[(size_t)c.x * CAP8 + pos0] = v0;
            else { const int o = atomicAdd(ovf_cnt, 1); if (o < OVF_MAX) ovf[o] = make_int2(c.x, (int)v0); }
            if (pos1 < CAP8) sl[(size_t)c.y * CAP8 + pos1] = v1;
            else { const int o = atomicAdd(ovf_cnt, 1); if (o < OVF_MAX) ovf[o] = make_int2(c.y, (int)v1); }
        } else {
            for (int e = base; e < E; ++e) {
                const int row = ei[e], colv = ei[(size_t)E + e];
                const int pos = atomicAdd(&cur[colv], 1);
                const unsigned v = (bf16_bits(attr[e]) << 16) | (unsigned)row;
                if (pos < CAP8) sl[(size_t)colv * CAP8 + pos] = v;
                else { const int o = atomicAdd(ovf_cnt, 1); if (o < OVF_MAX) ovf[o] = make_int2(colv, (int)v); }
            }
        }
    } else {
        // node pre-GEMM: 16 nodes/block, 256 threads (half -> P bf16, half -> Q fp32)
        __shared__ float xs[NPB][C];
        const int pb = blockIdx.x - SB;
        const int n0 = pb * NPB;
        const int tt = threadIdx.x & (C - 1);
        const int half = threadIdx.x >> 7;
        for (int i = threadIdx.x; i < NPB * C; i += 256) {
            const int gi = n0 * C + i;
            xs[0][i] = (gi < N * C) ? __builtin_nontemporal_load(x + gi) : 0.f;
        }
        __syncthreads();
        const float* __restrict__ Wb = W1 + (half ? (C * C) : 0) + tt;
        float acc[NPB] = {};
        for (int k = 0; k < C; ++k) {
            const float w = Wb[k * C];
#pragma unroll
            for (int j = 0; j < NPB; ++j)
                acc[j] = fmaf(xs[j][k], w, acc[j]);
        }
#pragma unroll
        for (int j = 0; j < NPB; ++j)
            if (n0 + j < N) {
                if (half) Q[(size_t)(n0 + j) * C + tt] = acc[j];
                else      P16[(size_t)(n0 + j) * C + tt] = (unsigned short)bf16_bits(acc[j]);
            }
    }
}

// Fused aggregation + output GEMM. 2 nodes per 256-thread block.
// Agg layout: per node, 8 slices x 16 lanes; slice s owns slab s; lane l owns
// channels [8l, 8l+8) via ONE 16B uint4 gather of bf16 P per edge.
// LDS-reduce 8 slices -> H, then k-sliced W2 matmul (4 slices x 32k x 4ch).
__global__ void agg_out_kernel(const unsigned* __restrict__ sorted, const int* __restrict__ cursor,
                               const unsigned short* __restrict__ P16, const float* __restrict__ Q,
                               const float* __restrict__ b1, const float* __restrict__ W2,
                               const float* __restrict__ b2,
                               const int* __restrict__ ovf_cnt, const int2* __restrict__ ovf,
                               float* __restrict__ out, int N) {
    __shared__ float part8[2][NSLAB][16][9];   // +1 pad: breaks stride-8 bank aliasing
    __shared__ float hs[2][C];
    __shared__ int   degs[2][NSLAB];
    __shared__ float4 part4[2][4][32];
    const int t = threadIdx.x;
    const int j = t >> 7;           // node within block
    const int s = (t >> 4) & 7;     // slab/slice
    const int l = t & 15;           // lane-group: channels [8l, 8l+8)
    const int n = blockIdx.x * 2 + j;

    float acc[8] = {};
    if (n < N) {
        const int rawcnt = cursor[(size_t)s * N + n];
        if (l == 0) degs[j][s] = rawcnt;
        const int cnt = min(rawcnt, CAP8);
        float qb[8];
        {
            const float4 qa = *(const float4*)(Q + (size_t)n * C + l * 8);
            const float4 qc = *(const float4*)(Q + (size_t)n * C + l * 8 + 4);
            const float4 ba = *(const float4*)(b1 + l * 8);
            const float4 bb = *(const float4*)(b1 + l * 8 + 4);
            qb[0] = qa.x + ba.x; qb[1] = qa.y + ba.y; qb[2] = qa.z + ba.z; qb[3] = qa.w + ba.w;
            qb[4] = qc.x + bb.x; qb[5] = qc.y + bb.y; qb[6] = qc.z + bb.z; qb[7] = qc.w + bb.w;
        }
        const unsigned* __restrict__ buf = sorted + ((size_t)s * N + n) * CAP8;
        for (int i = 0; i < cnt; ++i) {
            const unsigned v = buf[i];
            const uint4 pw = *(const uint4*)(P16 + (((size_t)(v & 0xFFFFu)) << 7) + l * 8);
            const float a = __uint_as_float(v & 0xFFFF0000u);
            const float p0 = __uint_as_float(pw.x << 16), p1 = __uint_as_float(pw.x & 0xFFFF0000u);
            const float p2 = __uint_as_float(pw.y << 16), p3 = __uint_as_float(pw.y & 0xFFFF0000u);
            const float p4 = __uint_as_float(pw.z << 16), p5 = __uint_as_float(pw.z & 0xFFFF0000u);
            const float p6 = __uint_as_float(pw.w << 16), p7 = __uint_as_float(pw.w & 0xFFFF0000u);
            acc[0] += fmaxf(fmaf(a, p0, qb[0]), 0.f);
            acc[1] += fmaxf(fmaf(a, p1, qb[1]), 0.f);
            acc[2] += fmaxf(fmaf(a, p2, qb[2]), 0.f);
            acc[3] += fmaxf(fmaf(a, p3, qb[3]), 0.f);
            acc[4] += fmaxf(fmaf(a, p4, qb[4]), 0.f);
            acc[5] += fmaxf(fmaf(a, p5, qb[5]), 0.f);
            acc[6] += fmaxf(fmaf(a, p6, qb[6]), 0.f);
            acc[7] += fmaxf(fmaf(a, p7, qb[7]), 0.f);
        }
        const int oc = min(*ovf_cnt, OVF_MAX);
        if (oc > 0 && s == 0) {      // statistically empty
            for (int o = 0; o < oc; ++o) {
                const int2 v = ovf[o];
                if (v.x == n) {
                    const unsigned u = (unsigned)v.y;
                    const uint4 pw = *(const uint4*)(P16 + (((size_t)(u & 0xFFFFu)) << 7) + l * 8);
                    const float a = __uint_as_float(u & 0xFFFF0000u);
                    acc[0] += fmaxf(fmaf(a, __uint_as_float(pw.x << 16), qb[0]), 0.f);
                    acc[1] += fmaxf(fmaf(a, __uint_as_float(pw.x & 0xFFFF0000u), qb[1]), 0.f);
                    acc[2] += fmaxf(fmaf(a, __uint_as_float(pw.y << 16), qb[2]), 0.f);
                    acc[3] += fmaxf(fmaf(a, __uint_as_float(pw.y & 0xFFFF0000u), qb[3]), 0.f);
                    acc[4] += fmaxf(fmaf(a, __uint_as_float(pw.z << 16), qb[4]), 0.f);
                    acc[5] += fmaxf(fmaf(a, __uint_as_float(pw.z & 0xFFFF0000u), qb[5]), 0.f);
                    acc[6] += fmaxf(fmaf(a, __uint_as_float(pw.w << 16), qb[6]), 0.f);
                    acc[7] += fmaxf(fmaf(a, __uint_as_float(pw.w & 0xFFFF0000u), qb[7]), 0.f);
                }
            }
        }
    }
#pragma unroll
    for (int k = 0; k < 8; ++k) part8[j][s][l][k] = acc[k];
    __syncthreads();
    // reduce 8 slices -> H[j][ch]
    {
        const int ch = t & 127;
        float h = 0.f;
#pragma unroll
        for (int ss = 0; ss < NSLAB; ++ss) h += part8[j][ss][ch >> 3][ch & 7];
        hs[j][ch] = h;
    }
    __syncthreads();
    // k-sliced W2 matmul: slice covers k in [32*slice, 32*slice+32), 4 ch/lane
    const int slice = (t >> 5) & 3;
    const int ch4 = t & 31;
    float4 o = make_float4(0.f, 0.f, 0.f, 0.f);
    if (n < N) {
        const int k0 = slice << 5;
#pragma unroll 8
        for (int k = k0; k < k0 + 32; ++k) {
            const float hv = hs[j][k];
            const float4 w = *(const float4*)(W2 + (size_t)k * C + (ch4 << 2));
            o.x = fmaf(hv, w.x, o.x);
            o.y = fmaf(hv, w.y, o.y);
            o.z = fmaf(hv, w.z, o.z);
            o.w = fmaf(hv, w.w, o.w);
        }
    }
    part4[j][slice][ch4] = o;
    __syncthreads();
    if (slice == 0 && n < N) {
        const float4 r0 = part4[j][0][ch4], r1 = part4[j][1][ch4];
        const float4 r2 = part4[j][2][ch4], r3 = part4[j][3][ch4];
        int deg = 0;
#pragma unroll
        for (int ss = 0; ss < NSLAB; ++ss) deg += degs[j][ss];
        const float4 b24 = *(const float4*)(b2 + (ch4 << 2));
        const float d = (float)deg;
        float4 res;
        res.x = fmaf(d, b24.x, r0.x + r1.x + r2.x + r3.x);
        res.y = fmaf(d, b24.y, r0.y + r1.y + r2.y + r3.y);
        res.z = fmaf(d, b24.z, r0.z + r1.z + r2.z + r3.z);
        res.w = fmaf(d, b24.w, r0.w + r1.w + r2.w + r3.w);
        *(float4*)(out + (size_t)n * C + (ch4 << 2)) = res;
    }
}

extern "C" void kernel_launch(void* const* d_in, const int* in_sizes, int n_in,
                              void* d_out, int out_size, void* d_ws, size_t ws_size,
                              hipStream_t stream) {
    const float* x    = (const float*)d_in[0];
    const int*   ei   = (const int*)d_in[1];
    const float* attr = (const float*)d_in[2];
    const float* W1   = (const float*)d_in[3];
    const float* b1   = (const float*)d_in[4];
    const float* W2   = (const float*)d_in[5];
    const float* b2   = (const float*)d_in[6];
    float* out = (float*)d_out;

    const int N = in_sizes[0] / C;
    const int E = in_sizes[2];

    char* ws = (char*)d_ws;
    unsigned short* P16 = (unsigned short*)ws;  ws += (size_t)N * C * sizeof(unsigned short);
    ws = (char*)(((uintptr_t)ws + 15) & ~(uintptr_t)15);
    float*    Q       = (float*)ws;     ws += (size_t)N * C * sizeof(float);
    unsigned* sorted  = (unsigned*)ws;  ws += (size_t)NSLAB * N * CAP8 * sizeof(unsigned);
    int2*     ovf     = (int2*)ws;      ws += (size_t)OVF_MAX * sizeof(int2);
    int*      cursor  = (int*)ws;       ws += (size_t)NSLAB * N * sizeof(int);
    int*      ovf_cnt = (int*)ws;

    (void)hipMemsetAsync(cursor, 0, ((size_t)NSLAB * N + 1) * sizeof(int), stream);

    const int SB = (E + 256 * EPT - 1) / (256 * EPT);   // 1250 scatter blocks
    const int PB = (N + NPB - 1) / NPB;                 // 625 GEMM blocks
    fused_pre_kernel<<<SB + PB, 256, 0, stream>>>(x, W1, P16, Q, ei, attr,
                                                  cursor, ovf_cnt, ovf, sorted, N, E, SB);
    agg_out_kernel<<<(N + 1) / 2, 256, 0, stream>>>(sorted, cursor, P16, Q, b1, W2, b2,
                                                    ovf_cnt, ovf, out, N);
}